// Round 1
// baseline (169.339 us; speedup 1.0000x reference)
//
#include <hip/hip_runtime.h>
#include <math.h>

// Forward kinematics chain: B=32768 batches, J=20 joints.
// out = concat(TrackingSE3 (B,10,4,4), RevSE3 (B,20,4,4), PriSE3 (B,20,4,4)) fp32.
// Memory-bound: ~105 MB stores + ~5.3 MB loads. One thread per batch element;
// per-joint constant transforms folded into LDS once per block.

constexpr int NJ = 20;

__device__ __forceinline__ void rpy2r_dev(float r, float p, float y, float R[9]) {
    float sr, cr, sp, cp, sy, cy;
    __sincosf(r, &sr, &cr);
    __sincosf(p, &sp, &cp);
    __sincosf(y, &sy, &cy);
    R[0] = cy * cp; R[1] = cy * sp * sr - sy * cr; R[2] = cy * sp * cr + sy * sr;
    R[3] = sy * cp; R[4] = sy * sp * sr + cy * cr; R[5] = sy * sp * cr - cy * sr;
    R[6] = -sp;     R[7] = cp * sr;                R[8] = cp * cr;
}

__device__ __forceinline__ void mat33_mul(const float A[9], const float B[9], float C[9]) {
#pragma unroll
    for (int i = 0; i < 3; ++i) {
        C[3 * i + 0] = A[3 * i + 0] * B[0] + A[3 * i + 1] * B[3] + A[3 * i + 2] * B[6];
        C[3 * i + 1] = A[3 * i + 0] * B[1] + A[3 * i + 1] * B[4] + A[3 * i + 2] * B[7];
        C[3 * i + 2] = A[3 * i + 0] * B[2] + A[3 * i + 1] * B[5] + A[3 * i + 2] * B[8];
    }
}

// LDS layout per joint (11 float4):
//  [0..2]  rev_T_off rows, p in .w
//  [3..5]  pri_T_off rows, p in .w
//  [6..8]  T_track rows, p in .w
//  [9]     normalized rev axis (xyz)
//  [10]    w = R_pri_off @ pri_axis (xyz)
__global__ __launch_bounds__(64) void fk_kernel(
    const float* __restrict__ rev_q,      const float* __restrict__ pri_q,
    const float* __restrict__ rev_p_off,  const float* __restrict__ rev_rpy_off,
    const float* __restrict__ pri_p_off,  const float* __restrict__ pri_rpy_off,
    const float* __restrict__ rev_axis,   const float* __restrict__ pri_axis,
    const float* __restrict__ p_track,    const float* __restrict__ rpy_track,
    float* __restrict__ out, int B)
{
    __shared__ float4 cst[NJ][11];
    const int t = threadIdx.x;

    if (t < NJ) {
        const int j = t;
        float Ro[9], Rp[9], Rt[9];
        rpy2r_dev(rev_rpy_off[3 * j], rev_rpy_off[3 * j + 1], rev_rpy_off[3 * j + 2], Ro);
        rpy2r_dev(pri_rpy_off[3 * j], pri_rpy_off[3 * j + 1], pri_rpy_off[3 * j + 2], Rp);
        rpy2r_dev(rpy_track[3 * j],   rpy_track[3 * j + 1],   rpy_track[3 * j + 2],   Rt);
        cst[j][0] = make_float4(Ro[0], Ro[1], Ro[2], rev_p_off[3 * j + 0]);
        cst[j][1] = make_float4(Ro[3], Ro[4], Ro[5], rev_p_off[3 * j + 1]);
        cst[j][2] = make_float4(Ro[6], Ro[7], Ro[8], rev_p_off[3 * j + 2]);
        cst[j][3] = make_float4(Rp[0], Rp[1], Rp[2], pri_p_off[3 * j + 0]);
        cst[j][4] = make_float4(Rp[3], Rp[4], Rp[5], pri_p_off[3 * j + 1]);
        cst[j][5] = make_float4(Rp[6], Rp[7], Rp[8], pri_p_off[3 * j + 2]);
        cst[j][6] = make_float4(Rt[0], Rt[1], Rt[2], p_track[3 * j + 0]);
        cst[j][7] = make_float4(Rt[3], Rt[4], Rt[5], p_track[3 * j + 1]);
        cst[j][8] = make_float4(Rt[6], Rt[7], Rt[8], p_track[3 * j + 2]);
        const float ax = rev_axis[3 * j], ay = rev_axis[3 * j + 1], az = rev_axis[3 * j + 2];
        const float inv = 1.0f / (sqrtf(ax * ax + ay * ay + az * az) + 1e-12f);
        cst[j][9] = make_float4(ax * inv, ay * inv, az * inv, 0.0f);
        const float px = pri_axis[3 * j], py = pri_axis[3 * j + 1], pz = pri_axis[3 * j + 2];
        cst[j][10] = make_float4(Rp[0] * px + Rp[1] * py + Rp[2] * pz,
                                 Rp[3] * px + Rp[4] * py + Rp[5] * pz,
                                 Rp[6] * px + Rp[7] * py + Rp[8] * pz, 0.0f);
    }
    __syncthreads();

    const int b = blockIdx.x * 64 + t;
    if (b >= B) return;

    // Preload joint values: 20 contiguous floats per thread (80 B, 16B-aligned).
    float rq[NJ], pq[NJ];
    {
        const float4* r4 = reinterpret_cast<const float4*>(rev_q + (size_t)b * NJ);
        const float4* p4 = reinterpret_cast<const float4*>(pri_q + (size_t)b * NJ);
#pragma unroll
        for (int i = 0; i < NJ / 4; ++i) {
            float4 a = r4[i];
            rq[4 * i + 0] = a.x; rq[4 * i + 1] = a.y; rq[4 * i + 2] = a.z; rq[4 * i + 3] = a.w;
            float4 c = p4[i];
            pq[4 * i + 0] = c.x; pq[4 * i + 1] = c.y; pq[4 * i + 2] = c.z; pq[4 * i + 3] = c.w;
        }
    }

    float TR[9] = {1, 0, 0, 0, 1, 0, 0, 0, 1};
    float Tp[3] = {0, 0, 0};

    float4* out4 = reinterpret_cast<float4*>(out);
    const size_t trkBase = (size_t)b * 40;                       // (b*10 + t)*4 + row
    const size_t revBase = (size_t)B * 40 + (size_t)b * 80;      // B*10*4 f4 offset
    const size_t priBase = (size_t)B * 120 + (size_t)b * 80;

#pragma unroll
    for (int j = 0; j < NJ; ++j) {
        // Revolute rotation: R = c I + s [a]x + (1-c) a a^T  (unit axis)
        float s, c;
        __sincosf(rq[j], &s, &c);
        const float4 a4 = cst[j][9];
        const float ax = a4.x, ay = a4.y, az = a4.z;
        const float omc = 1.0f - c;
        float Rr[9];
        Rr[0] = c + omc * ax * ax;      Rr[1] = omc * ax * ay - s * az; Rr[2] = omc * ax * az + s * ay;
        Rr[3] = omc * ax * ay + s * az; Rr[4] = c + omc * ay * ay;      Rr[5] = omc * ay * az - s * ax;
        Rr[6] = omc * ax * az - s * ay; Rr[7] = omc * ay * az + s * ax; Rr[8] = c + omc * az * az;

        // out1 = T @ (rev_T_off @ rev_T):  R1 = (TR@Roff)@Rr,  p1 = TR@poff + Tp
        const float4 cr0 = cst[j][0], cr1 = cst[j][1], cr2 = cst[j][2];
        const float Roff[9] = {cr0.x, cr0.y, cr0.z, cr1.x, cr1.y, cr1.z, cr2.x, cr2.y, cr2.z};
        float Ra[9], R1[9], p1[3];
        mat33_mul(TR, Roff, Ra);
        mat33_mul(Ra, Rr, R1);
#pragma unroll
        for (int i = 0; i < 3; ++i)
            p1[i] = fmaf(TR[3 * i + 0], cr0.w,
                    fmaf(TR[3 * i + 1], cr1.w,
                    fmaf(TR[3 * i + 2], cr2.w, Tp[i])));

        out4[revBase + 4 * j + 0] = make_float4(R1[0], R1[1], R1[2], p1[0]);
        out4[revBase + 4 * j + 1] = make_float4(R1[3], R1[4], R1[5], p1[1]);
        out4[revBase + 4 * j + 2] = make_float4(R1[6], R1[7], R1[8], p1[2]);
        out4[revBase + 4 * j + 3] = make_float4(0.f, 0.f, 0.f, 1.f);

        // out2 = out1 @ (pri_T_off @ pri_T):  R2 = R1@Rpoff,  p2 = R1@(q*w + ppoff) + p1
        const float4 cp0 = cst[j][3], cp1 = cst[j][4], cp2 = cst[j][5];
        const float4 w4 = cst[j][10];
        const float qp = pq[j];
        const float pstep[3] = {fmaf(qp, w4.x, cp0.w), fmaf(qp, w4.y, cp1.w), fmaf(qp, w4.z, cp2.w)};
        const float Rpoff[9] = {cp0.x, cp0.y, cp0.z, cp1.x, cp1.y, cp1.z, cp2.x, cp2.y, cp2.z};
        float R2[9], p2[3];
        mat33_mul(R1, Rpoff, R2);
#pragma unroll
        for (int i = 0; i < 3; ++i)
            p2[i] = fmaf(R1[3 * i + 0], pstep[0],
                    fmaf(R1[3 * i + 1], pstep[1],
                    fmaf(R1[3 * i + 2], pstep[2], p1[i])));

        out4[priBase + 4 * j + 0] = make_float4(R2[0], R2[1], R2[2], p2[0]);
        out4[priBase + 4 * j + 1] = make_float4(R2[3], R2[4], R2[5], p2[1]);
        out4[priBase + 4 * j + 2] = make_float4(R2[6], R2[7], R2[8], p2[2]);
        out4[priBase + 4 * j + 3] = make_float4(0.f, 0.f, 0.f, 1.f);

        // Tracking frame on even joints: trk = out2 @ T_track
        if ((j & 1) == 0) {
            const float4 ct0 = cst[j][6], ct1 = cst[j][7], ct2 = cst[j][8];
            const float Rtrk[9] = {ct0.x, ct0.y, ct0.z, ct1.x, ct1.y, ct1.z, ct2.x, ct2.y, ct2.z};
            float R3[9], p3[3];
            mat33_mul(R2, Rtrk, R3);
#pragma unroll
            for (int i = 0; i < 3; ++i)
                p3[i] = fmaf(R2[3 * i + 0], ct0.w,
                        fmaf(R2[3 * i + 1], ct1.w,
                        fmaf(R2[3 * i + 2], ct2.w, p2[i])));
            const size_t tb = trkBase + 4 * (size_t)(j >> 1);
            out4[tb + 0] = make_float4(R3[0], R3[1], R3[2], p3[0]);
            out4[tb + 1] = make_float4(R3[3], R3[4], R3[5], p3[1]);
            out4[tb + 2] = make_float4(R3[6], R3[7], R3[8], p3[2]);
            out4[tb + 3] = make_float4(0.f, 0.f, 0.f, 1.f);
        }

        // carry
#pragma unroll
        for (int i = 0; i < 9; ++i) TR[i] = R2[i];
#pragma unroll
        for (int i = 0; i < 3; ++i) Tp[i] = p2[i];
    }
}

extern "C" void kernel_launch(void* const* d_in, const int* in_sizes, int n_in,
                              void* d_out, int out_size, void* d_ws, size_t ws_size,
                              hipStream_t stream) {
    (void)n_in; (void)out_size; (void)d_ws; (void)ws_size;
    const float* rev_q       = (const float*)d_in[0];
    const float* pri_q       = (const float*)d_in[1];
    const float* rev_p_off   = (const float*)d_in[2];
    const float* rev_rpy_off = (const float*)d_in[3];
    const float* pri_p_off   = (const float*)d_in[4];
    const float* pri_rpy_off = (const float*)d_in[5];
    const float* rev_axis    = (const float*)d_in[6];
    const float* pri_axis    = (const float*)d_in[7];
    const float* p_track     = (const float*)d_in[8];
    const float* rpy_track   = (const float*)d_in[9];

    const int B = in_sizes[0] / NJ;              // 32768
    const int blocks = (B + 63) / 64;            // 512
    fk_kernel<<<dim3(blocks), dim3(64), 0, stream>>>(
        rev_q, pri_q, rev_p_off, rev_rpy_off, pri_p_off, pri_rpy_off,
        rev_axis, pri_axis, p_track, rpy_track, (float*)d_out, B);
}

// Round 2
// 152.038 us; speedup vs baseline: 1.1138x; 1.1138x over previous
//
#include <hip/hip_runtime.h>
#include <math.h>

// Forward kinematics chain: B=32768 batches, J=20 joints.
// out = concat(TrackingSE3 (B,10,4,4), RevSE3 (B,20,4,4), PriSE3 (B,20,4,4)) fp32.
//
// Two-phase single kernel:
//   Phase A: wave 0 of each block walks the serial 20-joint chain for 64
//            batches, storing the 12-float prefix state T_{j-1} per joint in
//            LDS (stride 244 floats/batch -> conflict-free b128 pattern).
//   Phase B: 256 threads = one per (batch, joint) pair x 5 iters recompute
//            rev/pri/track outputs from the prefix and store. Consecutive
//            lanes own consecutive joints -> wave covers contiguous spans,
//            L2 merges full lines (kills the 1.66x write amplification).

constexpr int NJ = 20;
constexpr int GB = 64;          // batches per block
constexpr int PREF_STRIDE = 61; // float4 per batch in prefix LDS (244 floats)

__device__ __forceinline__ void rpy2r_dev(float r, float p, float y, float R[9]) {
    float sr, cr, sp, cp, sy, cy;
    __sincosf(r, &sr, &cr);
    __sincosf(p, &sp, &cp);
    __sincosf(y, &sy, &cy);
    R[0] = cy * cp; R[1] = cy * sp * sr - sy * cr; R[2] = cy * sp * cr + sy * sr;
    R[3] = sy * cp; R[4] = sy * sp * sr + cy * cr; R[5] = sy * sp * cr - cy * sr;
    R[6] = -sp;     R[7] = cp * sr;                R[8] = cp * cr;
}

__device__ __forceinline__ void mat33_mul(const float A[9], const float B[9], float C[9]) {
#pragma unroll
    for (int i = 0; i < 3; ++i) {
        C[3 * i + 0] = A[3 * i + 0] * B[0] + A[3 * i + 1] * B[3] + A[3 * i + 2] * B[6];
        C[3 * i + 1] = A[3 * i + 0] * B[1] + A[3 * i + 1] * B[4] + A[3 * i + 2] * B[7];
        C[3 * i + 2] = A[3 * i + 0] * B[2] + A[3 * i + 1] * B[5] + A[3 * i + 2] * B[8];
    }
}

// cst layout per joint (11 float4):
//  [0..2] rev_T_off rows (p in .w)  [3..5] pri_T_off rows (p in .w)
//  [6..8] T_track rows (p in .w)    [9] unit rev axis      [10] R_pri_off@pri_axis
__global__ __launch_bounds__(256) void fk_kernel(
    const float* __restrict__ rev_q,      const float* __restrict__ pri_q,
    const float* __restrict__ rev_p_off,  const float* __restrict__ rev_rpy_off,
    const float* __restrict__ pri_p_off,  const float* __restrict__ pri_rpy_off,
    const float* __restrict__ rev_axis,   const float* __restrict__ pri_axis,
    const float* __restrict__ p_track,    const float* __restrict__ rpy_track,
    float* __restrict__ out, int B)
{
    __shared__ float4 cst[NJ][11];
    __shared__ float4 pre4[GB * PREF_STRIDE];   // 62,464 B: T_{j-1} rows, p in .w
    __shared__ float  sRq[GB * NJ];             // 5,120 B
    __shared__ float  sPq[GB * NJ];             // 5,120 B

    const int t = threadIdx.x;

    if (t < NJ) {
        const int j = t;
        float Ro[9], Rp[9], Rt[9];
        rpy2r_dev(rev_rpy_off[3 * j], rev_rpy_off[3 * j + 1], rev_rpy_off[3 * j + 2], Ro);
        rpy2r_dev(pri_rpy_off[3 * j], pri_rpy_off[3 * j + 1], pri_rpy_off[3 * j + 2], Rp);
        rpy2r_dev(rpy_track[3 * j],   rpy_track[3 * j + 1],   rpy_track[3 * j + 2],   Rt);
        cst[j][0] = make_float4(Ro[0], Ro[1], Ro[2], rev_p_off[3 * j + 0]);
        cst[j][1] = make_float4(Ro[3], Ro[4], Ro[5], rev_p_off[3 * j + 1]);
        cst[j][2] = make_float4(Ro[6], Ro[7], Ro[8], rev_p_off[3 * j + 2]);
        cst[j][3] = make_float4(Rp[0], Rp[1], Rp[2], pri_p_off[3 * j + 0]);
        cst[j][4] = make_float4(Rp[3], Rp[4], Rp[5], pri_p_off[3 * j + 1]);
        cst[j][5] = make_float4(Rp[6], Rp[7], Rp[8], pri_p_off[3 * j + 2]);
        cst[j][6] = make_float4(Rt[0], Rt[1], Rt[2], p_track[3 * j + 0]);
        cst[j][7] = make_float4(Rt[3], Rt[4], Rt[5], p_track[3 * j + 1]);
        cst[j][8] = make_float4(Rt[6], Rt[7], Rt[8], p_track[3 * j + 2]);
        const float ax = rev_axis[3 * j], ay = rev_axis[3 * j + 1], az = rev_axis[3 * j + 2];
        const float inv = 1.0f / (sqrtf(ax * ax + ay * ay + az * az) + 1e-12f);
        cst[j][9] = make_float4(ax * inv, ay * inv, az * inv, 0.0f);
        const float px = pri_axis[3 * j], py = pri_axis[3 * j + 1], pz = pri_axis[3 * j + 2];
        cst[j][10] = make_float4(Rp[0] * px + Rp[1] * py + Rp[2] * pz,
                                 Rp[3] * px + Rp[4] * py + Rp[5] * pz,
                                 Rp[6] * px + Rp[7] * py + Rp[8] * pz, 0.0f);
    }
    __syncthreads();

    const int blockBase = blockIdx.x * GB;

    // ---------------- Phase A: wave 0 walks the serial chain ----------------
    if (t < GB) {
        const int b = blockBase + t;
        if (b < B) {
            // load joint values, mirror into LDS
            float rq[NJ], pq[NJ];
            const float4* r4 = reinterpret_cast<const float4*>(rev_q + (size_t)b * NJ);
            const float4* p4 = reinterpret_cast<const float4*>(pri_q + (size_t)b * NJ);
            float4* sR4 = reinterpret_cast<float4*>(&sRq[t * NJ]);
            float4* sP4 = reinterpret_cast<float4*>(&sPq[t * NJ]);
#pragma unroll
            for (int i = 0; i < NJ / 4; ++i) {
                float4 a = r4[i]; sR4[i] = a;
                rq[4 * i] = a.x; rq[4 * i + 1] = a.y; rq[4 * i + 2] = a.z; rq[4 * i + 3] = a.w;
                float4 c = p4[i]; sP4[i] = c;
                pq[4 * i] = c.x; pq[4 * i + 1] = c.y; pq[4 * i + 2] = c.z; pq[4 * i + 3] = c.w;
            }

            float TR[9] = {1, 0, 0, 0, 1, 0, 0, 0, 1};
            float Tp[3] = {0, 0, 0};
#pragma unroll
            for (int j = 0; j < NJ; ++j) {
                // store prefix T_{j-1}
                float4* pr = &pre4[t * PREF_STRIDE + j * 3];
                pr[0] = make_float4(TR[0], TR[1], TR[2], Tp[0]);
                pr[1] = make_float4(TR[3], TR[4], TR[5], Tp[1]);
                pr[2] = make_float4(TR[6], TR[7], TR[8], Tp[2]);

                float s, c;
                __sincosf(rq[j], &s, &c);
                const float4 a4 = cst[j][9];
                const float ax = a4.x, ay = a4.y, az = a4.z, omc = 1.0f - c;
                float Rr[9];
                Rr[0] = c + omc * ax * ax;      Rr[1] = omc * ax * ay - s * az; Rr[2] = omc * ax * az + s * ay;
                Rr[3] = omc * ax * ay + s * az; Rr[4] = c + omc * ay * ay;      Rr[5] = omc * ay * az - s * ax;
                Rr[6] = omc * ax * az - s * ay; Rr[7] = omc * ay * az + s * ax; Rr[8] = c + omc * az * az;

                const float4 cr0 = cst[j][0], cr1 = cst[j][1], cr2 = cst[j][2];
                const float Roff[9] = {cr0.x, cr0.y, cr0.z, cr1.x, cr1.y, cr1.z, cr2.x, cr2.y, cr2.z};
                float Ra[9], R1[9], p1[3];
                mat33_mul(TR, Roff, Ra);
                mat33_mul(Ra, Rr, R1);
#pragma unroll
                for (int i = 0; i < 3; ++i)
                    p1[i] = fmaf(TR[3 * i], cr0.w, fmaf(TR[3 * i + 1], cr1.w, fmaf(TR[3 * i + 2], cr2.w, Tp[i])));

                const float4 cp0 = cst[j][3], cp1 = cst[j][4], cp2 = cst[j][5];
                const float4 w4 = cst[j][10];
                const float qp = pq[j];
                const float pstep[3] = {fmaf(qp, w4.x, cp0.w), fmaf(qp, w4.y, cp1.w), fmaf(qp, w4.z, cp2.w)};
                const float Rpoff[9] = {cp0.x, cp0.y, cp0.z, cp1.x, cp1.y, cp1.z, cp2.x, cp2.y, cp2.z};
                float R2[9];
                mat33_mul(R1, Rpoff, R2);
#pragma unroll
                for (int i = 0; i < 3; ++i)
                    Tp[i] = fmaf(R1[3 * i], pstep[0], fmaf(R1[3 * i + 1], pstep[1], fmaf(R1[3 * i + 2], pstep[2], p1[i])));
#pragma unroll
                for (int i = 0; i < 9; ++i) TR[i] = R2[i];
            }
        }
    }
    __syncthreads();

    // ---------------- Phase B: one thread per (batch, joint) pair ----------------
    float4* out4 = reinterpret_cast<float4*>(out);
    const int npairs = GB * NJ;   // 1280 = 5 * 256
#pragma unroll
    for (int it = 0; it < npairs / 256; ++it) {
        const int p = it * 256 + t;
        const int bl = (p * 3277) >> 16;     // p / 20 for p < 1280
        const int j = p - bl * 20;
        const int b = blockBase + bl;
        if (b >= B) continue;

        const float4* pr = &pre4[bl * PREF_STRIDE + j * 3];
        const float4 t0 = pr[0], t1 = pr[1], t2 = pr[2];
        const float TbR[9] = {t0.x, t0.y, t0.z, t1.x, t1.y, t1.z, t2.x, t2.y, t2.z};
        const float Tbp[3] = {t0.w, t1.w, t2.w};

        float s, c;
        __sincosf(sRq[bl * NJ + j], &s, &c);
        const float4 a4 = cst[j][9];
        const float ax = a4.x, ay = a4.y, az = a4.z, omc = 1.0f - c;
        float Rr[9];
        Rr[0] = c + omc * ax * ax;      Rr[1] = omc * ax * ay - s * az; Rr[2] = omc * ax * az + s * ay;
        Rr[3] = omc * ax * ay + s * az; Rr[4] = c + omc * ay * ay;      Rr[5] = omc * ay * az - s * ax;
        Rr[6] = omc * ax * az - s * ay; Rr[7] = omc * ay * az + s * ax; Rr[8] = c + omc * az * az;

        const float4 cr0 = cst[j][0], cr1 = cst[j][1], cr2 = cst[j][2];
        const float Roff[9] = {cr0.x, cr0.y, cr0.z, cr1.x, cr1.y, cr1.z, cr2.x, cr2.y, cr2.z};
        float Ra[9], R1[9], p1[3];
        mat33_mul(TbR, Roff, Ra);
        mat33_mul(Ra, Rr, R1);
#pragma unroll
        for (int i = 0; i < 3; ++i)
            p1[i] = fmaf(TbR[3 * i], cr0.w, fmaf(TbR[3 * i + 1], cr1.w, fmaf(TbR[3 * i + 2], cr2.w, Tbp[i])));

        const size_t revBase = (size_t)B * 40 + (size_t)b * 80 + (size_t)j * 4;
        out4[revBase + 0] = make_float4(R1[0], R1[1], R1[2], p1[0]);
        out4[revBase + 1] = make_float4(R1[3], R1[4], R1[5], p1[1]);
        out4[revBase + 2] = make_float4(R1[6], R1[7], R1[8], p1[2]);
        out4[revBase + 3] = make_float4(0.f, 0.f, 0.f, 1.f);

        const float4 cp0 = cst[j][3], cp1 = cst[j][4], cp2 = cst[j][5];
        const float4 w4 = cst[j][10];
        const float qp = sPq[bl * NJ + j];
        const float pstep[3] = {fmaf(qp, w4.x, cp0.w), fmaf(qp, w4.y, cp1.w), fmaf(qp, w4.z, cp2.w)};
        const float Rpoff[9] = {cp0.x, cp0.y, cp0.z, cp1.x, cp1.y, cp1.z, cp2.x, cp2.y, cp2.z};
        float R2[9], p2[3];
        mat33_mul(R1, Rpoff, R2);
#pragma unroll
        for (int i = 0; i < 3; ++i)
            p2[i] = fmaf(R1[3 * i], pstep[0], fmaf(R1[3 * i + 1], pstep[1], fmaf(R1[3 * i + 2], pstep[2], p1[i])));

        const size_t priBase = (size_t)B * 120 + (size_t)b * 80 + (size_t)j * 4;
        out4[priBase + 0] = make_float4(R2[0], R2[1], R2[2], p2[0]);
        out4[priBase + 1] = make_float4(R2[3], R2[4], R2[5], p2[1]);
        out4[priBase + 2] = make_float4(R2[6], R2[7], R2[8], p2[2]);
        out4[priBase + 3] = make_float4(0.f, 0.f, 0.f, 1.f);

        if ((j & 1) == 0) {
            const float4 ct0 = cst[j][6], ct1 = cst[j][7], ct2 = cst[j][8];
            const float Rtrk[9] = {ct0.x, ct0.y, ct0.z, ct1.x, ct1.y, ct1.z, ct2.x, ct2.y, ct2.z};
            float R3[9], p3[3];
            mat33_mul(R2, Rtrk, R3);
#pragma unroll
            for (int i = 0; i < 3; ++i)
                p3[i] = fmaf(R2[3 * i], ct0.w, fmaf(R2[3 * i + 1], ct1.w, fmaf(R2[3 * i + 2], ct2.w, p2[i])));
            const size_t tb = (size_t)b * 40 + (size_t)(j >> 1) * 4;
            out4[tb + 0] = make_float4(R3[0], R3[1], R3[2], p3[0]);
            out4[tb + 1] = make_float4(R3[3], R3[4], R3[5], p3[1]);
            out4[tb + 2] = make_float4(R3[6], R3[7], R3[8], p3[2]);
            out4[tb + 3] = make_float4(0.f, 0.f, 0.f, 1.f);
        }
    }
}

extern "C" void kernel_launch(void* const* d_in, const int* in_sizes, int n_in,
                              void* d_out, int out_size, void* d_ws, size_t ws_size,
                              hipStream_t stream) {
    (void)n_in; (void)out_size; (void)d_ws; (void)ws_size;
    const float* rev_q       = (const float*)d_in[0];
    const float* pri_q       = (const float*)d_in[1];
    const float* rev_p_off   = (const float*)d_in[2];
    const float* rev_rpy_off = (const float*)d_in[3];
    const float* pri_p_off   = (const float*)d_in[4];
    const float* pri_rpy_off = (const float*)d_in[5];
    const float* rev_axis    = (const float*)d_in[6];
    const float* pri_axis    = (const float*)d_in[7];
    const float* p_track     = (const float*)d_in[8];
    const float* rpy_track   = (const float*)d_in[9];

    const int B = in_sizes[0] / NJ;              // 32768
    const int blocks = (B + GB - 1) / GB;        // 512
    fk_kernel<<<dim3(blocks), dim3(256), 0, stream>>>(
        rev_q, pri_q, rev_p_off, rev_rpy_off, pri_p_off, pri_rpy_off,
        rev_axis, pri_axis, p_track, rpy_track, (float*)d_out, B);
}

// Round 3
// 149.861 us; speedup vs baseline: 1.1300x; 1.0145x over previous
//
#include <hip/hip_runtime.h>
#include <math.h>

// Forward kinematics chain: B=32768 batches, J=20 joints.
// out = concat(TrackingSE3 (B,10,4,4), RevSE3 (B,20,4,4), PriSE3 (B,20,4,4)) fp32.
//
// Wave-parallel design: one lane per (batch, joint). The serial 20-joint chain
// T_j = S_0 @ S_1 @ ... @ S_j (S_j = rev_off @ rodrigues(q) @ pri_off @ pri(q),
// affine 3x3+p) is computed as a Kogge-Stone inclusive scan across 20 lanes
// (5 shfl_up rounds, width=32 -> 2 batches per wave64). No prefix LDS, no
// serial phase: occupancy is VGPR-bound and every wave streams stores.

constexpr int NJ = 20;
constexpr int BPB = 8;   // batches per block (256 threads / 32-lane groups)

struct Aff { float R[9]; float p[3]; };

__device__ __forceinline__ void rpy2r_dev(float r, float p, float y, float R[9]) {
    float sr, cr, sp, cp, sy, cy;
    __sincosf(r, &sr, &cr);
    __sincosf(p, &sp, &cp);
    __sincosf(y, &sy, &cy);
    R[0] = cy * cp; R[1] = cy * sp * sr - sy * cr; R[2] = cy * sp * cr + sy * sr;
    R[3] = sy * cp; R[4] = sy * sp * sr + cy * cr; R[5] = sy * sp * cr - cy * sr;
    R[6] = -sp;     R[7] = cp * sr;                R[8] = cp * cr;
}

__device__ __forceinline__ void mat33_mul(const float A[9], const float B[9], float C[9]) {
#pragma unroll
    for (int i = 0; i < 3; ++i) {
        C[3 * i + 0] = A[3 * i + 0] * B[0] + A[3 * i + 1] * B[3] + A[3 * i + 2] * B[6];
        C[3 * i + 1] = A[3 * i + 0] * B[1] + A[3 * i + 1] * B[4] + A[3 * i + 2] * B[7];
        C[3 * i + 2] = A[3 * i + 0] * B[2] + A[3 * i + 1] * B[5] + A[3 * i + 2] * B[8];
    }
}

// C = A @ B for affine (R, p): C.R = A.R@B.R, C.p = A.R@B.p + A.p
__device__ __forceinline__ Aff compose(const Aff& A, const Aff& B) {
    Aff C;
    mat33_mul(A.R, B.R, C.R);
#pragma unroll
    for (int i = 0; i < 3; ++i)
        C.p[i] = fmaf(A.R[3 * i + 0], B.p[0],
                 fmaf(A.R[3 * i + 1], B.p[1],
                 fmaf(A.R[3 * i + 2], B.p[2], A.p[i])));
    return C;
}

__device__ __forceinline__ Aff shfl_up_aff(const Aff& V, int d) {
    Aff N;
#pragma unroll
    for (int k = 0; k < 9; ++k) N.R[k] = __shfl_up(V.R[k], d, 32);
#pragma unroll
    for (int k = 0; k < 3; ++k) N.p[k] = __shfl_up(V.p[k], d, 32);
    return N;
}

// cst layout per joint (11 float4):
//  [0..2] rev_T_off rows (p in .w)  [3..5] pri_T_off rows (p in .w)
//  [6..8] T_track rows (p in .w)    [9] unit rev axis      [10] R_pri_off@pri_axis
__global__ __launch_bounds__(256) void fk_scan_kernel(
    const float* __restrict__ rev_q,      const float* __restrict__ pri_q,
    const float* __restrict__ rev_p_off,  const float* __restrict__ rev_rpy_off,
    const float* __restrict__ pri_p_off,  const float* __restrict__ pri_rpy_off,
    const float* __restrict__ rev_axis,   const float* __restrict__ pri_axis,
    const float* __restrict__ p_track,    const float* __restrict__ rpy_track,
    float* __restrict__ out, int B)
{
    __shared__ float4 cst[NJ][11];
    const int t = threadIdx.x;

    if (t < NJ) {
        const int j = t;
        float Ro[9], Rp[9], Rt[9];
        rpy2r_dev(rev_rpy_off[3 * j], rev_rpy_off[3 * j + 1], rev_rpy_off[3 * j + 2], Ro);
        rpy2r_dev(pri_rpy_off[3 * j], pri_rpy_off[3 * j + 1], pri_rpy_off[3 * j + 2], Rp);
        rpy2r_dev(rpy_track[3 * j],   rpy_track[3 * j + 1],   rpy_track[3 * j + 2],   Rt);
        cst[j][0] = make_float4(Ro[0], Ro[1], Ro[2], rev_p_off[3 * j + 0]);
        cst[j][1] = make_float4(Ro[3], Ro[4], Ro[5], rev_p_off[3 * j + 1]);
        cst[j][2] = make_float4(Ro[6], Ro[7], Ro[8], rev_p_off[3 * j + 2]);
        cst[j][3] = make_float4(Rp[0], Rp[1], Rp[2], pri_p_off[3 * j + 0]);
        cst[j][4] = make_float4(Rp[3], Rp[4], Rp[5], pri_p_off[3 * j + 1]);
        cst[j][5] = make_float4(Rp[6], Rp[7], Rp[8], pri_p_off[3 * j + 2]);
        cst[j][6] = make_float4(Rt[0], Rt[1], Rt[2], p_track[3 * j + 0]);
        cst[j][7] = make_float4(Rt[3], Rt[4], Rt[5], p_track[3 * j + 1]);
        cst[j][8] = make_float4(Rt[6], Rt[7], Rt[8], p_track[3 * j + 2]);
        const float ax = rev_axis[3 * j], ay = rev_axis[3 * j + 1], az = rev_axis[3 * j + 2];
        const float inv = 1.0f / (sqrtf(ax * ax + ay * ay + az * az) + 1e-12f);
        cst[j][9] = make_float4(ax * inv, ay * inv, az * inv, 0.0f);
        const float px = pri_axis[3 * j], py = pri_axis[3 * j + 1], pz = pri_axis[3 * j + 2];
        cst[j][10] = make_float4(Rp[0] * px + Rp[1] * py + Rp[2] * pz,
                                 Rp[3] * px + Rp[4] * py + Rp[5] * pz,
                                 Rp[6] * px + Rp[7] * py + Rp[8] * pz, 0.0f);
    }
    __syncthreads();

    const int j = t & 31;                    // joint lane within width-32 group
    const int b = blockIdx.x * BPB + (t >> 5);
    if (j >= NJ || b >= B) return;           // lanes 20..31 idle; shfl sources are all < 20

    const float rq = rev_q[(size_t)b * NJ + j];
    const float pq = pri_q[(size_t)b * NJ + j];

    // --- per-joint local step ---
    float s, c;
    __sincosf(rq, &s, &c);
    const float4 a4 = cst[j][9];
    const float ax = a4.x, ay = a4.y, az = a4.z, omc = 1.0f - c;
    float Rr[9];
    Rr[0] = c + omc * ax * ax;      Rr[1] = omc * ax * ay - s * az; Rr[2] = omc * ax * az + s * ay;
    Rr[3] = omc * ax * ay + s * az; Rr[4] = c + omc * ay * ay;      Rr[5] = omc * ay * az - s * ax;
    Rr[6] = omc * ax * az - s * ay; Rr[7] = omc * ay * az + s * ax; Rr[8] = c + omc * az * az;

    const float4 cr0 = cst[j][0], cr1 = cst[j][1], cr2 = cst[j][2];
    const float Roff[9] = {cr0.x, cr0.y, cr0.z, cr1.x, cr1.y, cr1.z, cr2.x, cr2.y, cr2.z};
    Aff revstep;                              // rev_T_off @ rodrigues(q)
    mat33_mul(Roff, Rr, revstep.R);
    revstep.p[0] = cr0.w; revstep.p[1] = cr1.w; revstep.p[2] = cr2.w;

    const float4 cp0 = cst[j][3], cp1 = cst[j][4], cp2 = cst[j][5];
    const float4 w4 = cst[j][10];
    const float Rpoff[9] = {cp0.x, cp0.y, cp0.z, cp1.x, cp1.y, cp1.z, cp2.x, cp2.y, cp2.z};
    const float pp[3] = {fmaf(pq, w4.x, cp0.w), fmaf(pq, w4.y, cp1.w), fmaf(pq, w4.z, cp2.w)};

    Aff V;                                    // S_j = revstep @ pristep
    mat33_mul(revstep.R, Rpoff, V.R);
#pragma unroll
    for (int i = 0; i < 3; ++i)
        V.p[i] = fmaf(revstep.R[3 * i + 0], pp[0],
                 fmaf(revstep.R[3 * i + 1], pp[1],
                 fmaf(revstep.R[3 * i + 2], pp[2], revstep.p[i])));

    // --- Kogge-Stone inclusive scan: V_j = S_0 @ ... @ S_j ---
#pragma unroll
    for (int d = 1; d < 32; d <<= 1) {
        Aff N = shfl_up_aff(V, d);
        if (j >= d) V = compose(N, V);
    }

    // --- RevSE3_j = V_{j-1} @ revstep_j  (V_{-1} = I) ---
    Aff P = shfl_up_aff(V, 1);
    if (j == 0) {
        P.R[0] = 1.f; P.R[1] = 0.f; P.R[2] = 0.f;
        P.R[3] = 0.f; P.R[4] = 1.f; P.R[5] = 0.f;
        P.R[6] = 0.f; P.R[7] = 0.f; P.R[8] = 1.f;
        P.p[0] = 0.f; P.p[1] = 0.f; P.p[2] = 0.f;
    }
    const Aff Rev = compose(P, revstep);

    float4* out4 = reinterpret_cast<float4*>(out);
    const float4 bot = make_float4(0.f, 0.f, 0.f, 1.f);

    const size_t revBase = (size_t)B * 40 + (size_t)b * 80 + (size_t)j * 4;
    out4[revBase + 0] = make_float4(Rev.R[0], Rev.R[1], Rev.R[2], Rev.p[0]);
    out4[revBase + 1] = make_float4(Rev.R[3], Rev.R[4], Rev.R[5], Rev.p[1]);
    out4[revBase + 2] = make_float4(Rev.R[6], Rev.R[7], Rev.R[8], Rev.p[2]);
    out4[revBase + 3] = bot;

    const size_t priBase = (size_t)B * 120 + (size_t)b * 80 + (size_t)j * 4;
    out4[priBase + 0] = make_float4(V.R[0], V.R[1], V.R[2], V.p[0]);
    out4[priBase + 1] = make_float4(V.R[3], V.R[4], V.R[5], V.p[1]);
    out4[priBase + 2] = make_float4(V.R[6], V.R[7], V.R[8], V.p[2]);
    out4[priBase + 3] = bot;

    if ((j & 1) == 0) {
        const float4 ct0 = cst[j][6], ct1 = cst[j][7], ct2 = cst[j][8];
        Aff T;
        T.R[0] = ct0.x; T.R[1] = ct0.y; T.R[2] = ct0.z;
        T.R[3] = ct1.x; T.R[4] = ct1.y; T.R[5] = ct1.z;
        T.R[6] = ct2.x; T.R[7] = ct2.y; T.R[8] = ct2.z;
        T.p[0] = ct0.w; T.p[1] = ct1.w; T.p[2] = ct2.w;
        const Aff Trk = compose(V, T);
        const size_t tb = (size_t)b * 40 + (size_t)(j >> 1) * 4;
        out4[tb + 0] = make_float4(Trk.R[0], Trk.R[1], Trk.R[2], Trk.p[0]);
        out4[tb + 1] = make_float4(Trk.R[3], Trk.R[4], Trk.R[5], Trk.p[1]);
        out4[tb + 2] = make_float4(Trk.R[6], Trk.R[7], Trk.R[8], Trk.p[2]);
        out4[tb + 3] = bot;
    }
}

extern "C" void kernel_launch(void* const* d_in, const int* in_sizes, int n_in,
                              void* d_out, int out_size, void* d_ws, size_t ws_size,
                              hipStream_t stream) {
    (void)n_in; (void)out_size; (void)d_ws; (void)ws_size;
    const float* rev_q       = (const float*)d_in[0];
    const float* pri_q       = (const float*)d_in[1];
    const float* rev_p_off   = (const float*)d_in[2];
    const float* rev_rpy_off = (const float*)d_in[3];
    const float* pri_p_off   = (const float*)d_in[4];
    const float* pri_rpy_off = (const float*)d_in[5];
    const float* rev_axis    = (const float*)d_in[6];
    const float* pri_axis    = (const float*)d_in[7];
    const float* p_track     = (const float*)d_in[8];
    const float* rpy_track   = (const float*)d_in[9];

    const int B = in_sizes[0] / NJ;                  // 32768
    const int blocks = (B + BPB - 1) / BPB;          // 4096
    fk_scan_kernel<<<dim3(blocks), dim3(256), 0, stream>>>(
        rev_q, pri_q, rev_p_off, rev_rpy_off, pri_p_off, pri_rpy_off,
        rev_axis, pri_axis, p_track, rpy_track, (float*)d_out, B);
}

// Round 5
// 139.183 us; speedup vs baseline: 1.2167x; 1.0767x over previous
//
#include <hip/hip_runtime.h>
#include <math.h>

// Forward kinematics chain: B=32768 batches, J=20 joints.
// out = concat(TrackingSE3 (B,10,4,4), RevSE3 (B,20,4,4), PriSE3 (B,20,4,4)) fp32.
//
// v3b: wave-parallel Kogge-Stone scan over joints + LDS-staged fully-coalesced
// output copy (lane-contiguous float4 nontemporal stores -> full 64B lines).
// Fix vs v3: __builtin_nontemporal_store needs a clang ext-vector type, not
// HIP's float4 class -> use v4f for the copy path.

constexpr int NJ  = 20;
constexpr int GB  = 8;     // batches per block (256 threads / 32-lane groups)
constexpr int BSTR = 151;  // float4 per batch in staging (60 rev + 60 pri + 30 trk + 1 pad)
constexpr int PRIO = 60;
constexpr int TRKO = 120;

typedef float v4f __attribute__((ext_vector_type(4)));

struct Aff { float R[9]; float p[3]; };

__device__ __forceinline__ void rpy2r_dev(float r, float p, float y, float R[9]) {
    float sr, cr, sp, cp, sy, cy;
    __sincosf(r, &sr, &cr);
    __sincosf(p, &sp, &cp);
    __sincosf(y, &sy, &cy);
    R[0] = cy * cp; R[1] = cy * sp * sr - sy * cr; R[2] = cy * sp * cr + sy * sr;
    R[3] = sy * cp; R[4] = sy * sp * sr + cy * cr; R[5] = sy * sp * cr - cy * sr;
    R[6] = -sp;     R[7] = cp * sr;                R[8] = cp * cr;
}

__device__ __forceinline__ void mat33_mul(const float A[9], const float B[9], float C[9]) {
#pragma unroll
    for (int i = 0; i < 3; ++i) {
        C[3 * i + 0] = A[3 * i + 0] * B[0] + A[3 * i + 1] * B[3] + A[3 * i + 2] * B[6];
        C[3 * i + 1] = A[3 * i + 0] * B[1] + A[3 * i + 1] * B[4] + A[3 * i + 2] * B[7];
        C[3 * i + 2] = A[3 * i + 0] * B[2] + A[3 * i + 1] * B[5] + A[3 * i + 2] * B[8];
    }
}

__device__ __forceinline__ Aff compose(const Aff& A, const Aff& B) {
    Aff C;
    mat33_mul(A.R, B.R, C.R);
#pragma unroll
    for (int i = 0; i < 3; ++i)
        C.p[i] = fmaf(A.R[3 * i + 0], B.p[0],
                 fmaf(A.R[3 * i + 1], B.p[1],
                 fmaf(A.R[3 * i + 2], B.p[2], A.p[i])));
    return C;
}

__device__ __forceinline__ Aff shfl_up_aff(const Aff& V, int d) {
    Aff N;
#pragma unroll
    for (int k = 0; k < 9; ++k) N.R[k] = __shfl_up(V.R[k], d, 32);
#pragma unroll
    for (int k = 0; k < 3; ++k) N.p[k] = __shfl_up(V.p[k], d, 32);
    return N;
}

// cst layout per joint (11 float4):
//  [0..2] rev_T_off rows (p in .w)  [3..5] pri_T_off rows (p in .w)
//  [6..8] T_track rows (p in .w)    [9] unit rev axis      [10] R_pri_off@pri_axis
__global__ __launch_bounds__(256) void fk_kernel(
    const float* __restrict__ rev_q,      const float* __restrict__ pri_q,
    const float* __restrict__ rev_p_off,  const float* __restrict__ rev_rpy_off,
    const float* __restrict__ pri_p_off,  const float* __restrict__ pri_rpy_off,
    const float* __restrict__ rev_axis,   const float* __restrict__ pri_axis,
    const float* __restrict__ p_track,    const float* __restrict__ rpy_track,
    float* __restrict__ out, int B)
{
    __shared__ float4 cst[NJ][11];
    __shared__ v4f stg[GB * BSTR];   // 19,328 B staging
    const int t = threadIdx.x;

    if (t < NJ) {
        const int j = t;
        float Ro[9], Rp[9], Rt[9];
        rpy2r_dev(rev_rpy_off[3 * j], rev_rpy_off[3 * j + 1], rev_rpy_off[3 * j + 2], Ro);
        rpy2r_dev(pri_rpy_off[3 * j], pri_rpy_off[3 * j + 1], pri_rpy_off[3 * j + 2], Rp);
        rpy2r_dev(rpy_track[3 * j],   rpy_track[3 * j + 1],   rpy_track[3 * j + 2],   Rt);
        cst[j][0] = make_float4(Ro[0], Ro[1], Ro[2], rev_p_off[3 * j + 0]);
        cst[j][1] = make_float4(Ro[3], Ro[4], Ro[5], rev_p_off[3 * j + 1]);
        cst[j][2] = make_float4(Ro[6], Ro[7], Ro[8], rev_p_off[3 * j + 2]);
        cst[j][3] = make_float4(Rp[0], Rp[1], Rp[2], pri_p_off[3 * j + 0]);
        cst[j][4] = make_float4(Rp[3], Rp[4], Rp[5], pri_p_off[3 * j + 1]);
        cst[j][5] = make_float4(Rp[6], Rp[7], Rp[8], pri_p_off[3 * j + 2]);
        cst[j][6] = make_float4(Rt[0], Rt[1], Rt[2], p_track[3 * j + 0]);
        cst[j][7] = make_float4(Rt[3], Rt[4], Rt[5], p_track[3 * j + 1]);
        cst[j][8] = make_float4(Rt[6], Rt[7], Rt[8], p_track[3 * j + 2]);
        const float ax = rev_axis[3 * j], ay = rev_axis[3 * j + 1], az = rev_axis[3 * j + 2];
        const float inv = 1.0f / (sqrtf(ax * ax + ay * ay + az * az) + 1e-12f);
        cst[j][9] = make_float4(ax * inv, ay * inv, az * inv, 0.0f);
        const float px = pri_axis[3 * j], py = pri_axis[3 * j + 1], pz = pri_axis[3 * j + 2];
        cst[j][10] = make_float4(Rp[0] * px + Rp[1] * py + Rp[2] * pz,
                                 Rp[3] * px + Rp[4] * py + Rp[5] * pz,
                                 Rp[6] * px + Rp[7] * py + Rp[8] * pz, 0.0f);
    }
    __syncthreads();

    const int j = t & 31;               // joint lane within width-32 group
    const int g = t >> 5;               // batch slot within block
    const int b = blockIdx.x * GB + g;  // B is a multiple of GB

    if (j < NJ) {
        const float rq = rev_q[(size_t)b * NJ + j];
        const float pq = pri_q[(size_t)b * NJ + j];

        // --- per-joint local step ---
        float s, c;
        __sincosf(rq, &s, &c);
        const float4 a4 = cst[j][9];
        const float ax = a4.x, ay = a4.y, az = a4.z, omc = 1.0f - c;
        float Rr[9];
        Rr[0] = c + omc * ax * ax;      Rr[1] = omc * ax * ay - s * az; Rr[2] = omc * ax * az + s * ay;
        Rr[3] = omc * ax * ay + s * az; Rr[4] = c + omc * ay * ay;      Rr[5] = omc * ay * az - s * ax;
        Rr[6] = omc * ax * az - s * ay; Rr[7] = omc * ay * az + s * ax; Rr[8] = c + omc * az * az;

        const float4 cr0 = cst[j][0], cr1 = cst[j][1], cr2 = cst[j][2];
        const float Roff[9] = {cr0.x, cr0.y, cr0.z, cr1.x, cr1.y, cr1.z, cr2.x, cr2.y, cr2.z};
        Aff revstep;                    // rev_T_off @ rodrigues(q)
        mat33_mul(Roff, Rr, revstep.R);
        revstep.p[0] = cr0.w; revstep.p[1] = cr1.w; revstep.p[2] = cr2.w;

        const float4 cp0 = cst[j][3], cp1 = cst[j][4], cp2 = cst[j][5];
        const float4 w4 = cst[j][10];
        const float Rpoff[9] = {cp0.x, cp0.y, cp0.z, cp1.x, cp1.y, cp1.z, cp2.x, cp2.y, cp2.z};
        const float pp[3] = {fmaf(pq, w4.x, cp0.w), fmaf(pq, w4.y, cp1.w), fmaf(pq, w4.z, cp2.w)};

        Aff V;                          // S_j = revstep @ pristep
        mat33_mul(revstep.R, Rpoff, V.R);
#pragma unroll
        for (int i = 0; i < 3; ++i)
            V.p[i] = fmaf(revstep.R[3 * i + 0], pp[0],
                     fmaf(revstep.R[3 * i + 1], pp[1],
                     fmaf(revstep.R[3 * i + 2], pp[2], revstep.p[i])));

        // --- Kogge-Stone inclusive scan: V_j = S_0 @ ... @ S_j ---
#pragma unroll
        for (int d = 1; d < 32; d <<= 1) {
            Aff N = shfl_up_aff(V, d);
            if (j >= d) V = compose(N, V);
        }

        // --- RevSE3_j = V_{j-1} @ revstep_j  (V_{-1} = I) ---
        Aff P = shfl_up_aff(V, 1);
        if (j == 0) {
            P.R[0] = 1.f; P.R[1] = 0.f; P.R[2] = 0.f;
            P.R[3] = 0.f; P.R[4] = 1.f; P.R[5] = 0.f;
            P.R[6] = 0.f; P.R[7] = 0.f; P.R[8] = 1.f;
            P.p[0] = 0.f; P.p[1] = 0.f; P.p[2] = 0.f;
        }
        const Aff Rev = compose(P, revstep);

        // --- stage rows 0..2 into LDS ---
        v4f* sg = &stg[g * BSTR];
        sg[3 * j + 0] = (v4f){Rev.R[0], Rev.R[1], Rev.R[2], Rev.p[0]};
        sg[3 * j + 1] = (v4f){Rev.R[3], Rev.R[4], Rev.R[5], Rev.p[1]};
        sg[3 * j + 2] = (v4f){Rev.R[6], Rev.R[7], Rev.R[8], Rev.p[2]};
        sg[PRIO + 3 * j + 0] = (v4f){V.R[0], V.R[1], V.R[2], V.p[0]};
        sg[PRIO + 3 * j + 1] = (v4f){V.R[3], V.R[4], V.R[5], V.p[1]};
        sg[PRIO + 3 * j + 2] = (v4f){V.R[6], V.R[7], V.R[8], V.p[2]};

        if ((j & 1) == 0) {
            const float4 ct0 = cst[j][6], ct1 = cst[j][7], ct2 = cst[j][8];
            Aff T;
            T.R[0] = ct0.x; T.R[1] = ct0.y; T.R[2] = ct0.z;
            T.R[3] = ct1.x; T.R[4] = ct1.y; T.R[5] = ct1.z;
            T.R[6] = ct2.x; T.R[7] = ct2.y; T.R[8] = ct2.z;
            T.p[0] = ct0.w; T.p[1] = ct1.w; T.p[2] = ct2.w;
            const Aff Trk = compose(V, T);
            const int jt = j >> 1;
            sg[TRKO + 3 * jt + 0] = (v4f){Trk.R[0], Trk.R[1], Trk.R[2], Trk.p[0]};
            sg[TRKO + 3 * jt + 1] = (v4f){Trk.R[3], Trk.R[4], Trk.R[5], Trk.p[1]};
            sg[TRKO + 3 * jt + 2] = (v4f){Trk.R[6], Trk.R[7], Trk.R[8], Trk.p[2]};
        }
    }
    __syncthreads();

    // --- cooperative, fully-coalesced copy: lane-contiguous float4 stores ---
    v4f* out4 = reinterpret_cast<v4f*>(out);
    const v4f bot = (v4f){0.f, 0.f, 0.f, 1.f};
    const int blockBase = blockIdx.x * GB;

    // Tracking span: GB*40 = 320 float4 at out4[blockBase*40]
    {
        v4f* dst = out4 + (size_t)blockBase * 40;
#pragma unroll
        for (int k = t; k < GB * 40; k += 256) {
            const int gg = k / 40, w = k - gg * 40;
            const int jt = w >> 2, r = w & 3;
            const v4f v = (r == 3) ? bot : stg[gg * BSTR + TRKO + 3 * jt + r];
            __builtin_nontemporal_store(v, &dst[k]);
        }
    }
    // Rev span: GB*80 = 640 float4 at out4[B*40 + blockBase*80]
    {
        v4f* dst = out4 + (size_t)B * 40 + (size_t)blockBase * 80;
#pragma unroll
        for (int k = t; k < GB * 80; k += 256) {
            const int gg = k / 80, w = k - gg * 80;
            const int jj = w >> 2, r = w & 3;
            const v4f v = (r == 3) ? bot : stg[gg * BSTR + 3 * jj + r];
            __builtin_nontemporal_store(v, &dst[k]);
        }
    }
    // Pri span: GB*80 = 640 float4 at out4[B*120 + blockBase*80]
    {
        v4f* dst = out4 + (size_t)B * 120 + (size_t)blockBase * 80;
#pragma unroll
        for (int k = t; k < GB * 80; k += 256) {
            const int gg = k / 80, w = k - gg * 80;
            const int jj = w >> 2, r = w & 3;
            const v4f v = (r == 3) ? bot : stg[gg * BSTR + PRIO + 3 * jj + r];
            __builtin_nontemporal_store(v, &dst[k]);
        }
    }
}

extern "C" void kernel_launch(void* const* d_in, const int* in_sizes, int n_in,
                              void* d_out, int out_size, void* d_ws, size_t ws_size,
                              hipStream_t stream) {
    (void)n_in; (void)out_size; (void)d_ws; (void)ws_size;
    const float* rev_q       = (const float*)d_in[0];
    const float* pri_q       = (const float*)d_in[1];
    const float* rev_p_off   = (const float*)d_in[2];
    const float* rev_rpy_off = (const float*)d_in[3];
    const float* pri_p_off   = (const float*)d_in[4];
    const float* pri_rpy_off = (const float*)d_in[5];
    const float* rev_axis    = (const float*)d_in[6];
    const float* pri_axis    = (const float*)d_in[7];
    const float* p_track     = (const float*)d_in[8];
    const float* rpy_track   = (const float*)d_in[9];

    const int B = in_sizes[0] / NJ;              // 32768 (multiple of GB)
    const int blocks = B / GB;                   // 4096
    fk_kernel<<<dim3(blocks), dim3(256), 0, stream>>>(
        rev_q, pri_q, rev_p_off, rev_rpy_off, pri_p_off, pri_rpy_off,
        rev_axis, pri_axis, p_track, rpy_track, (float*)d_out, B);
}